// Round 12
// baseline (112.492 us; speedup 1.0000x reference)
//
#include <hip/hip_runtime.h>

#define SMOOTH 1e-5f

typedef float floatx4 __attribute__((ext_vector_type(4)));
typedef float floatx2 __attribute__((ext_vector_type(2)));

// d_ws layout: [0..600)          float partials ws[scale][img][5]
//              [4096..4096+1MB)  packed target bits: [img*512+row][64 bytes]

__device__ __forceinline__ float wave_reduce(float v) {
#pragma unroll
    for (int off = 32; off; off >>= 1) v += __shfl_down(v, off, 64);
    return v;
}

__device__ __forceinline__ float sigmoidf(float x) {
    return 1.f / (1.f + __expf(-x));
}

__device__ __forceinline__ unsigned pack8(int4 a, int4 b) {
    return (unsigned)(a.x != 0)        | ((unsigned)(a.y != 0) << 1) |
           ((unsigned)(a.z != 0) << 2) | ((unsigned)(a.w != 0) << 3) |
           ((unsigned)(b.x != 0) << 4) | ((unsigned)(b.y != 0) << 5) |
           ((unsigned)(b.z != 0) << 6) | ((unsigned)(b.w != 0) << 7);
}
// ds1 bits (even cols): byte bits {0,2,4,6} -> {0,1,2,3}
__device__ __forceinline__ unsigned even4(unsigned b) {
    return (b & 1u) | ((b >> 1) & 2u) | ((b >> 2) & 4u) | ((b >> 3) & 8u);
}
// ds2 bits (cols 0,4): byte bits {0,4} -> {0,1}
__device__ __forceinline__ unsigned ext2(unsigned b) {
    return (b & 1u) | ((b >> 3) & 2u);
}

template<int W>
__device__ __forceinline__ int stencil_cnt(unsigned u, unsigned c, unsigned d, int lane)
{
    unsigned pv = __shfl_up(c, 1);
    unsigned nx = __shfl_down(c, 1);
    if (lane == 0)  pv = 0;
    if (lane == 63) nx = 0;
    const unsigned M = (1u << W) - 1u;
    unsigned lv = ((c << 1) | ((pv >> (W - 1)) & 1u)) & M;
    unsigned rv = ((c >> 1) | ((nx & 1u) << (W - 1))) & M;
    return __popc(c & ~(u & d & lv & rv));
}

__device__ __forceinline__ void acc_row8(floatx4 a, floatx4 b, unsigned bits,
                                         float& I, float& Z, float& P) {
    float pr[8] = {sigmoidf(a.x), sigmoidf(a.y), sigmoidf(a.z), sigmoidf(a.w),
                   sigmoidf(b.x), sigmoidf(b.y), sigmoidf(b.z), sigmoidf(b.w)};
#pragma unroll
    for (int j = 0; j < 8; ++j) {
        I += ((bits >> j) & 1u) ? pr[j] : 0.f;
        Z += pr[j] * pr[j];
        P += pr[j];
    }
}
__device__ __forceinline__ void acc_row4(floatx4 a, unsigned bits,
                                         float& I, float& Z, float& P) {
    float pr[4] = {sigmoidf(a.x), sigmoidf(a.y), sigmoidf(a.z), sigmoidf(a.w)};
#pragma unroll
    for (int j = 0; j < 4; ++j) {
        I += ((bits >> j) & 1u) ? pr[j] : 0.f;
        Z += pr[j] * pr[j];
        P += pr[j];
    }
}
__device__ __forceinline__ void acc_row2(floatx2 a, unsigned bits,
                                         float& I, float& Z, float& P) {
    float pr[2] = {sigmoidf(a.x), sigmoidf(a.y)};
#pragma unroll
    for (int j = 0; j < 2; ++j) {
        I += ((bits >> j) & 1u) ? pr[j] : 0.f;
        Z += pr[j] * pr[j];
        P += pr[j];
    }
}

// ---- pass 1: pack targets to 1 bit/px. One wave = one full row (512 px).
// Pure linear: 2x int4 loads/lane, 1 byte store/lane. 4096 blocks x 4 waves.
__global__ __launch_bounds__(256) void pack_tgt(
    const int* __restrict__ tgt, unsigned char* __restrict__ packed)
{
    const int gw   = blockIdx.x * 4 + (threadIdx.x >> 6);   // global row 0..16383
    const int lane = threadIdx.x & 63;
    const int* src = tgt + (size_t)gw * 512 + lane * 8;
    int4 a = *(const int4*)(src);
    int4 b = *(const int4*)(src + 4);
    packed[(size_t)gw * 64 + lane] = (unsigned char)pack8(a, b);
}

// ---- pass 2: unified (R11 structure), target stencil from packed bytes.
// 1024 blocks x 256 thr; wave = full row width, 4-row strip; all 15 partials.
// Per lane: 8 x 1B packed rows (L2-hot) + 11 logit vector loads.
__global__ __launch_bounds__(256) void bdou_unified(
    const float* __restrict__ l0, const float* __restrict__ l1,
    const float* __restrict__ l2, const unsigned char* __restrict__ packed,
    float* __restrict__ ws)
{
    const int blk  = blockIdx.x;
    const int tid  = threadIdx.x;
    const int w    = tid >> 6, lane = tid & 63;
    const int img  = blk >> 5;
    const int y0   = (blk & 31) * 16 + w * 4;          // 0..508, mult of 4

    const unsigned char* P = packed + (size_t)img * (512 * 64) + lane;
    const float* L0 = l0 + (size_t)img * 262144 + lane * 8;
    const float* L1 = l1 + (size_t)img * 65536  + lane * 4;
    const float* L2 = l2 + (size_t)img * 16384  + lane * 2;

    const int ym4 = (y0 >= 4) ? y0 - 4 : 0;
    const int ym2 = (y0 >= 2) ? y0 - 2 : 0;
    const int ym1 = (y0 >= 1) ? y0 - 1 : 0;
    const int yp4 = (y0 + 4 <= 511) ? y0 + 4 : 511;
    const unsigned mu = (y0 > 0)   ? 0xFFu : 0u;
    const unsigned md = (y0 < 508) ? 0xFFu : 0u;

    // ---- 8 packed-row loads (1B/lane) + 11 logit loads ----
    unsigned bm4 = P[(size_t)ym4 * 64];
    unsigned bm2 = P[(size_t)ym2 * 64];
    unsigned bm1 = P[(size_t)ym1 * 64];
    unsigned b0  = P[(size_t)(y0    ) * 64];
    unsigned b1  = P[(size_t)(y0 + 1) * 64];
    unsigned b2  = P[(size_t)(y0 + 2) * 64];
    unsigned b3  = P[(size_t)(y0 + 3) * 64];
    unsigned bp4 = P[(size_t)yp4 * 64];
    floatx4 g00 = *(const floatx4*)(L0 + (size_t)(y0    ) * 512), g01 = *(const floatx4*)(L0 + (size_t)(y0    ) * 512 + 4);
    floatx4 g10 = *(const floatx4*)(L0 + (size_t)(y0 + 1) * 512), g11 = *(const floatx4*)(L0 + (size_t)(y0 + 1) * 512 + 4);
    floatx4 g20 = *(const floatx4*)(L0 + (size_t)(y0 + 2) * 512), g21 = *(const floatx4*)(L0 + (size_t)(y0 + 2) * 512 + 4);
    floatx4 g30 = *(const floatx4*)(L0 + (size_t)(y0 + 3) * 512), g31 = *(const floatx4*)(L0 + (size_t)(y0 + 3) * 512 + 4);
    floatx4 h0  = *(const floatx4*)(L1 + (size_t)(y0 / 2    ) * 256);
    floatx4 h1  = *(const floatx4*)(L1 + (size_t)(y0 / 2 + 1) * 256);
    floatx2 q0  = *(const floatx2*)(L2 + (size_t)(y0 / 4) * 128);

    bm4 &= mu; bm2 &= mu; bm1 &= mu; bp4 &= md;

    int cC0, cS0, cC1, cS1, cC2, cS2;
    float aI0 = 0.f, aZ0 = 0.f, aP0 = 0.f;
    float aI1 = 0.f, aZ1 = 0.f, aP1 = 0.f;
    float aI2 = 0.f, aZ2 = 0.f, aP2 = 0.f;

    // scale 0
    cS0 = __popc(b0) + __popc(b1) + __popc(b2) + __popc(b3);
    cC0 = stencil_cnt<8>(bm1, b0, b1, lane) + stencil_cnt<8>(b0, b1, b2, lane) +
          stencil_cnt<8>(b1, b2, b3, lane) + stencil_cnt<8>(b2, b3, bp4, lane);
    acc_row8(g00, g01, b0, aI0, aZ0, aP0);
    acc_row8(g10, g11, b1, aI0, aZ0, aP0);
    acc_row8(g20, g21, b2, aI0, aZ0, aP0);
    acc_row8(g30, g31, b3, aI0, aZ0, aP0);

    // scale 1 (ds rows y0/2, y0/2+1 <- full rows y0, y0+2)
    {
        unsigned cu = even4(bm2), c0 = even4(b0), c1 = even4(b2), cd = even4(bp4);
        cS1 = __popc(c0) + __popc(c1);
        cC1 = stencil_cnt<4>(cu, c0, c1, lane) + stencil_cnt<4>(c0, c1, cd, lane);
        acc_row4(h0, c0, aI1, aZ1, aP1);
        acc_row4(h1, c1, aI1, aZ1, aP1);
    }

    // scale 2 (ds row y0/4 <- full row y0)
    {
        unsigned zu = ext2(bm4), z = ext2(b0), zd = ext2(bp4);
        cS2 = __popc(z);
        cC2 = stencil_cnt<2>(zu, z, zd, lane);
        acc_row2(q0, z, aI2, aZ2, aP2);
    }

    float vals[15] = {(float)cC0, (float)cS0, aI0, aZ0, aP0,
                      (float)cC1, (float)cS1, aI1, aZ1, aP1,
                      (float)cC2, (float)cS2, aI2, aZ2, aP2};
    __shared__ float red[4][15];
#pragma unroll
    for (int k = 0; k < 15; ++k) vals[k] = wave_reduce(vals[k]);
    if (lane == 0) {
#pragma unroll
        for (int k = 0; k < 15; ++k) red[w][k] = vals[k];
    }
    __syncthreads();
    if (tid < 15) {
        float s = red[0][tid] + red[1][tid] + red[2][tid] + red[3][tid];
        int sc = tid / 5, k = tid - sc * 5;
        atomicAdd(&ws[(sc * 32 + img) * 5 + k], s);
    }
}

// 128 threads: tid<96 -> one (scale,img) pair each; wave+LDS reduce.
__global__ void bdou_final(const float* __restrict__ ws,
                           const float* __restrict__ valid_mask,
                           float* __restrict__ out)
{
    int tid = threadIdx.x;
    float contrib = 0.f, cpart = 0.f;
    if (tid < 96) {
        int s = tid >> 5, i = tid & 31;
        const float* w = ws + tid * 5;
        float C = w[0], S = w[1], I = w[2], Z = w[3], P = w[4];
        float valid = (valid_mask[i] >= 0.5f) ? 1.f : 0.f;
        float alpha = fminf(2.f * (1.f - (C + SMOOTH) / (S + SMOOTH)) - 1.f, 0.8f);
        float dou = (Z + S - 2.f * I + SMOOTH) /
                    (Z + S - (1.f + alpha) * I + SMOOTH);
        const float wts[3]  = {4.f / 7.f, 2.f / 7.f, 1.f / 7.f};
        const float pixc[3] = {262144.f, 65536.f, 16384.f};
        float per = (S > 0.f) ? dou : (P / pixc[s]);
        contrib = wts[s] * per * valid;
        if (tid < 32) cpart = valid;
    }
    contrib = wave_reduce(contrib);
    cpart   = wave_reduce(cpart);
    __shared__ float sm[2][2];
    int wv = tid >> 6, ln = tid & 63;
    if (ln == 0) { sm[wv][0] = contrib; sm[wv][1] = cpart; }
    __syncthreads();
    if (tid == 0) {
        float tot = sm[0][0] + sm[1][0];
        float cnt = sm[0][1] + sm[1][1];
        out[0] = (cnt > 0.f) ? tot / cnt : 0.f;
    }
}

extern "C" void kernel_launch(void* const* d_in, const int* in_sizes, int n_in,
                              void* d_out, int out_size, void* d_ws, size_t ws_size,
                              hipStream_t stream) {
    const float* l0 = (const float*)d_in[0];
    const float* l1 = (const float*)d_in[1];
    const float* l2 = (const float*)d_in[2];
    const int*   tg = (const int*)d_in[3];
    const float* vm = (const float*)d_in[4];
    float* ws = (float*)d_ws;
    unsigned char* packed = (unsigned char*)d_ws + 4096;

    (void)hipMemsetAsync(ws, 0, 3 * 32 * 5 * sizeof(float), stream);
    pack_tgt<<<4096, 256, 0, stream>>>(tg, packed);
    bdou_unified<<<1024, 256, 0, stream>>>(l0, l1, l2, packed, ws);
    bdou_final<<<1, 128, 0, stream>>>(ws, vm, (float*)d_out);
}